// Round 3
// baseline (216.690 us; speedup 1.0000x reference)
//
#include <hip/hip_runtime.h>

// Problem constants (reference: E=3.2M, N=100k, B=64). B must be compile-time
// for the LDS accumulator; E,N taken from in_sizes at runtime.
#define NG 64
#define ACC_STRIDE 7   // 6 symmetric components, stride 7 (coprime to 32 banks)

__global__ void zero_out_kernel(float* __restrict__ out, int n) {
    int i = blockIdx.x * blockDim.x + threadIdx.x;
    if (i < n) out[i] = 0.0f;
}

__global__ __launch_bounds__(256) void virial_kernel(
    const float* __restrict__ disp,       // E*3
    const float* __restrict__ edge_w,     // E
    const int*   __restrict__ edge_index, // 2*E (row0 = src, row1 = dst)
    const int*   __restrict__ batch,      // N (sorted graph id per atom)
    float* __restrict__ out,              // 64*9
    int E)
{
    __shared__ float acc[NG * ACC_STRIDE];
    for (int i = threadIdx.x; i < NG * ACC_STRIDE; i += blockDim.x) acc[i] = 0.0f;
    __syncthreads();

    const int nquads = E >> 2;           // E % 4 handled in tail
    const int tid    = blockIdx.x * blockDim.x + threadIdx.x;
    const int stride = gridDim.x * blockDim.x;

    const float4* __restrict__ disp4 = (const float4*)disp;
    const float4* __restrict__ w4    = (const float4*)edge_w;
    const int4*   __restrict__ src4  = (const int4*)edge_index;
    const int4*   __restrict__ dst4  = (const int4*)(edge_index + E);

    for (int q = tid; q < nquads; q += stride) {
        float4 d0 = disp4[q * 3 + 0];
        float4 d1 = disp4[q * 3 + 1];
        float4 d2 = disp4[q * 3 + 2];
        float4 w  = w4[q];
        int4   s  = src4[q];
        int4   t  = dst4[q];

        float dx[4] = {d0.x, d0.w, d1.z, d2.y};
        float dy[4] = {d0.y, d1.x, d1.w, d2.z};
        float dz[4] = {d0.z, d1.y, d2.x, d2.w};
        float ww[4] = {w.x,  w.y,  w.z,  w.w};
        int   ss[4] = {s.x,  s.y,  s.z,  s.w};
        int   tt[4] = {t.x,  t.y,  t.z,  t.w};

#pragma unroll
        for (int k = 0; k < 4; ++k) {
            float c  = -2.0f * ww[k];
            float xx = c * dx[k] * dx[k];
            float xy = c * dx[k] * dy[k];
            float xz = c * dx[k] * dz[k];
            float yy = c * dy[k] * dy[k];
            float yz = c * dy[k] * dz[k];
            float zz = c * dz[k] * dz[k];
            int g0 = batch[ss[k]];
            int g1 = batch[tt[k]];
            float* a0 = &acc[g0 * ACC_STRIDE];
            atomicAdd(a0 + 0, xx); atomicAdd(a0 + 1, xy); atomicAdd(a0 + 2, xz);
            atomicAdd(a0 + 3, yy); atomicAdd(a0 + 4, yz); atomicAdd(a0 + 5, zz);
            float* a1 = &acc[g1 * ACC_STRIDE];
            atomicAdd(a1 + 0, xx); atomicAdd(a1 + 1, xy); atomicAdd(a1 + 2, xz);
            atomicAdd(a1 + 3, yy); atomicAdd(a1 + 4, yz); atomicAdd(a1 + 5, zz);
        }
    }

    // Tail edges (E % 4), handled by the first few threads globally.
    const int tail_start = nquads << 2;
    if (tid < (E - tail_start)) {
        int e = tail_start + tid;
        float ddx = disp[e * 3 + 0], ddy = disp[e * 3 + 1], ddz = disp[e * 3 + 2];
        float c = -2.0f * edge_w[e];
        int g0 = batch[edge_index[e]];
        int g1 = batch[edge_index[E + e]];
        float xx = c * ddx * ddx, xy = c * ddx * ddy, xz = c * ddx * ddz;
        float yy = c * ddy * ddy, yz = c * ddy * ddz, zz = c * ddz * ddz;
        float* a0 = &acc[g0 * ACC_STRIDE];
        atomicAdd(a0 + 0, xx); atomicAdd(a0 + 1, xy); atomicAdd(a0 + 2, xz);
        atomicAdd(a0 + 3, yy); atomicAdd(a0 + 4, yz); atomicAdd(a0 + 5, zz);
        float* a1 = &acc[g1 * ACC_STRIDE];
        atomicAdd(a1 + 0, xx); atomicAdd(a1 + 1, xy); atomicAdd(a1 + 2, xz);
        atomicAdd(a1 + 3, yy); atomicAdd(a1 + 4, yz); atomicAdd(a1 + 5, zz);
    }

    __syncthreads();

    // Block partial -> global (expand 6 symmetric components to full 3x3).
    for (int i = threadIdx.x; i < NG * 9; i += blockDim.x) {
        int g = i / 9, ij = i % 9, r = ij / 3, cc = ij % 3;
        int lo = r < cc ? r : cc;
        int hi = r < cc ? cc : r;
        // (0,0)->0 (0,1)->1 (0,2)->2 (1,1)->3 (1,2)->4 (2,2)->5
        int comp = (lo == 0) ? hi : ((lo == 1) ? 2 + hi : 5);
        atomicAdd(&out[i], acc[g * ACC_STRIDE + comp]);
    }
}

extern "C" void kernel_launch(void* const* d_in, const int* in_sizes, int n_in,
                              void* d_out, int out_size, void* d_ws, size_t ws_size,
                              hipStream_t stream) {
    const float* disp       = (const float*)d_in[0];
    const float* edge_w     = (const float*)d_in[1];
    const int*   edge_index = (const int*)d_in[2];
    const int*   batch      = (const int*)d_in[3];
    float*       out        = (float*)d_out;

    const int E = in_sizes[1];   // edge_w count

    // d_out is poisoned before timing and not re-zeroed between replays:
    // zero it ourselves every call.
    zero_out_kernel<<<(NG * 9 + 255) / 256, 256, 0, stream>>>(out, NG * 9);

    const int blocks = 1024;     // 4 blocks/CU, grid-stride over E/4 quads
    virial_kernel<<<blocks, 256, 0, stream>>>(disp, edge_w, edge_index, batch, out, E);
}